// Round 2
// baseline (235.651 us; speedup 1.0000x reference)
//
#include <hip/hip_runtime.h>
#include <hip/hip_cooperative_groups.h>
#include <stdint.h>

namespace cg = cooperative_groups;

// DirectionLoss: mask -> Zhang-Suen (bit-sliced, LDS-tiled 128x128-own tiles,
// per-substep block-local early exit, per-tile activity skip) -> fused
// direction-trigger + weighted CE reduce.
// NEW: all 8 thinning macros fused into ONE cooperative kernel with grid.sync
// between macros and a global-convergence break (anyChg flag), eliminating
// 7 dispatch gaps + ~6 nearly-empty skip-macro dispatches.
//
// Global bit layout per image: padded rows [1032][18] u64 (4 pad rows each side,
// 1 pad word each side), interior word (y,k): y in [0,1024), k in [0,16).
// ws: anyChg (8 ints) at 0; bitA, bitB at +1024 (each 4*18576 u64); chgA, chgB.

#define IMG_B 4
#define IMG_H 1024
#define IMG_W 1024
#define HW (IMG_H * IMG_W)
#define NPIX (IMG_B * HW)
#define TPB 256
#define KW 18
#define ROWS 1032
#define IMG_WORDS (KW * ROWS)          // 18576
#define NW_INT (IMG_B * IMG_H * 16)    // 65536 interior words

// thinning: own 128x128 per tile, halo 32 -> region 192x192, <=16 iters/macro
#define R_ITERS 16
#define MACROS 8                       // 8*16 = 128 = MAX_THIN_ITERS
#define NTILES 256                     // 8x8x4, one block per tile
#define TTPB 576                       // 192 rows x 3 words, 1 word/thread
#define TLW2 5                         // LDS u64 per row: [pad, w0, w1, w2, pad]
#define TROWS2 194
#define TW2 (TROWS2 * TLW2)            // 970

__device__ __forceinline__ uint64_t* wadr(uint64_t* img, int y, int k) {
    return img + (size_t)(y + 4) * KW + (k + 1);
}
__device__ __forceinline__ const uint64_t* wadr(const uint64_t* img, int y, int k) {
    return img + (size_t)(y + 4) * KW + (k + 1);
}

__device__ __forceinline__ uint64_t eq2_5(uint64_t a, uint64_t b, uint64_t c,
                                          uint64_t d, uint64_t e) {
    uint64_t ab = a ^ b;
    uint64_t s1 = ab ^ c;
    uint64_t c1 = (a & b) | (c & ab);
    uint64_t t1 = s1 & d;
    uint64_t s2 = s1 ^ d;
    uint64_t t2 = s2 & e;
    uint64_t s3 = s2 ^ e;
    uint64_t ct = c1 ^ t1;
    uint64_t w2s = ct ^ t2;
    uint64_t w2c = (c1 & t1) | (t2 & ct);
    return ~s3 & w2s & ~w2c;
}

__device__ __forceinline__ uint64_t thin_core(uint64_t nL, uint64_t nC, uint64_t nR,
                                              uint64_t cL, uint64_t cC, uint64_t cR,
                                              uint64_t sL, uint64_t sC, uint64_t sR,
                                              int sub, uint64_t* cond_out) {
    uint64_t P2 = nC, P6 = sC;
    uint64_t P9 = (nC << 1) | (nL >> 63), P3 = (nC >> 1) | (nR << 63);
    uint64_t P8 = (cC << 1) | (cL >> 63), P4 = (cC >> 1) | (cR << 63);
    uint64_t P7 = (sC << 1) | (sL >> 63), P5 = (sC >> 1) | (sR << 63);

    // Bc in [2,6] via bitsliced 8-way popcount
    uint64_t sa = P2 ^ P3, ca = P2 & P3;
    uint64_t sb = P4 ^ P5, cb = P4 & P5;
    uint64_t sc2 = P6 ^ P7, cc2 = P6 & P7;
    uint64_t sd = P8 ^ P9, cd = P8 & P9;
    uint64_t t0x = sa & sb, u0 = sa ^ sb;
    uint64_t v0x = ca ^ cb, v0 = v0x ^ t0x;
    uint64_t w0 = (ca & cb) | (t0x & v0x);
    uint64_t t1x = sc2 & sd, u1 = sc2 ^ sd;
    uint64_t v1x = cc2 ^ cd, v1 = v1x ^ t1x;
    uint64_t w1 = (cc2 & cd) | (t1x & v1x);
    uint64_t b0 = u0 ^ u1, g0 = u0 & u1;
    uint64_t b1x = v0 ^ v1, b1 = b1x ^ g0;
    uint64_t g1 = (v0 & v1) | (g0 & b1x);
    uint64_t b2x = w0 ^ w1, b2 = b2x ^ g1;
    uint64_t b3 = (w0 & w1) | (g1 & b2x);
    uint64_t ge2 = b1 | b2 | b3;
    uint64_t le6 = ~(b3 | (b2 & b1 & b0));

    // A == 1: exactly one 0->1 transition around the ring (shallow tree)
    uint64_t t0 = ~P2 & P3, t1 = ~P3 & P4, t2 = ~P4 & P5, t3 = ~P5 & P6;
    uint64_t t4 = ~P6 & P7, t5 = ~P7 & P8, t6 = ~P8 & P9, t7 = ~P9 & P2;
    uint64_t s0 = t0 | t1, d0 = t0 & t1;
    uint64_t s1 = t2 | t3, d1 = t2 & t3;
    uint64_t s2 = t4 | t5, d2 = t4 & t5;
    uint64_t s3 = t6 | t7, d3 = t6 & t7;
    uint64_t sA = s0 | s1, dA = d0 | d1 | (s0 & s1);
    uint64_t sB = s2 | s3, dB = d2 | d3 | (s2 & s3);
    uint64_t any1 = sA | sB;
    uint64_t any2 = dA | dB | (sA & sB);
    uint64_t A1 = any1 & ~any2;

    uint64_t cond = cC & ge2 & le6 & A1;
    if (sub == 0) cond &= ~(P2 & P4 & P6) & ~(P4 & P6 & P8);
    else          cond &= ~(P2 & P4 & P8) & ~(P2 & P6 & P8);
    *cond_out = cond;
    return cC & ~cond;
}

template<int DY, int DX>
__device__ __forceinline__ uint64_t dir_trig(const uint64_t* r, int y, int k) {
    uint64_t sh[9];
    uint64_t any = 0;
    #pragma unroll
    for (int j = -4; j <= 4; ++j) {
        const uint64_t* rr = r + j * DY * KW;
        const int s = j * DX;
        uint64_t w = rr[0], v;
        if (s > 0)      v = (w >> s) | (rr[1] << (64 - s));
        else if (s < 0) v = (w << (-s)) | (rr[-1] >> (64 + s));
        else            v = w;
        sh[j + 4] = v; any |= v;
    }
    if (!any) return 0;
    uint64_t trig = 0;
    #pragma unroll
    for (int o = -2; o <= 2; ++o) {
        uint64_t E = eq2_5(sh[o + 2], sh[o + 3], sh[o + 4], sh[o + 5], sh[o + 6]);
        if (DY != 0) {
            int qy = y + o * DY;
            if ((unsigned)qy >= (unsigned)IMG_H) E = 0;
        }
        const int s = o * DX;
        if (s < 0)      { if (k == 0)  E &= (~0ull) << (-s); }
        else if (s > 0) { if (k == 15) E &= (~0ull) >> s; }
        trig |= E;
    }
    return trig;
}

// ---- kernel A: zero pads of both bit buffers, build mask bitmap ----
__global__ __launch_bounds__(TPB) void mask_kernel(const float* __restrict__ logits,
                                                   uint64_t* __restrict__ bitA,
                                                   uint64_t* __restrict__ bitB) {
    const int gtid = blockIdx.x * TPB + threadIdx.x;
    const int gsz = gridDim.x * TPB;
    const int wid = gtid >> 6, lane = gtid & 63, nwv = gsz >> 6;

    for (int i = gtid; i < IMG_B * IMG_WORDS; i += gsz) {
        int w = i % IMG_WORDS;
        int row = w / KW, col = w - row * KW;
        if (row < 4 || row >= ROWS - 4 || col == 0 || col == KW - 1) {
            bitA[i] = 0; bitB[i] = 0;
        }
    }
    for (int w = wid; w < NW_INT; w += nwv) {
        int b = w >> 14, r2 = w & 16383, y = r2 >> 4, k = r2 & 15;
        int rem = (y << 10) + (k << 6) + lane;
        const float* p0 = logits + (size_t)(2 * b) * HW + rem;
        float l0 = p0[0], l1 = p0[HW];
        uint64_t mask = __ballot(l1 >= l0);
        if (lane == 0) *wadr(bitA + (size_t)b * IMG_WORDS, y, k) = mask;
    }
}

// ---- kernel B: ALL thinning macros in one cooperative kernel ----
__global__ __launch_bounds__(TTPB) void thin_coop(uint64_t* __restrict__ bitA,
                                                  uint64_t* __restrict__ bitB,
                                                  uint8_t* __restrict__ chgA,
                                                  uint8_t* __restrict__ chgB,
                                                  int* __restrict__ anyChg) {
    cg::grid_group grid = cg::this_grid();
    __shared__ uint64_t lbuf[2][TW2];
    __shared__ int sflag;
    const int tile = blockIdx.x;
    const int tx = tile & 7, ty = (tile >> 3) & 7, tb = tile >> 6;
    const int r = 1 + (int)threadIdx.x / 3, jl = (int)threadIdx.x % 3;
    const int ci = r * TLW2 + 1 + jl;
    const uint64_t omask = (jl == 0) ? 0xFFFFFFFF00000000ull
                         : (jl == 1) ? ~0ull : 0x00000000FFFFFFFFull;
    const bool own_r = (r >= 33) && (r <= 160);

    #pragma unroll 1
    for (int m = 0; m < MACROS; ++m) {
        const uint64_t* gin = (m & 1) ? bitB : bitA;
        uint64_t* gout = (m & 1) ? bitA : bitB;
        const uint8_t* chgPrev = (m & 1) ? chgA : chgB;   // written at macro m-1
        uint8_t* chgCur = (m & 1) ? chgB : chgA;          // written at macro m

        bool active = true;
        if (m > 0) {
            if (threadIdx.x == 0) sflag = 0;
            __syncthreads();
            if (threadIdx.x < 9) {
                int dxn = (int)threadIdx.x % 3 - 1, dyn = (int)threadIdx.x / 3 - 1;
                int nx = tx + dxn, ny = ty + dyn;
                if ((unsigned)nx < 8u && (unsigned)ny < 8u &&
                    chgPrev[tb * 64 + ny * 8 + nx]) sflag = 1;  // benign race
            }
            __syncthreads();
            active = (sflag != 0);      // neighborhood static -> skip macro;
        }                               // skip-invariant: both buffers identical

        if (active) {
            // zero LDS pads (never overwritten afterwards)
            for (int i = threadIdx.x; i < TW2; i += TTPB) {
                int c = i % TLW2, rr = i / TLW2;
                if (c == 0 || c == TLW2 - 1 || rr == 0 || rr == TROWS2 - 1) {
                    lbuf[0][i] = 0; lbuf[1][i] = 0;
                }
            }
            // load region 192 rows x 3 words: thread t -> (r = 1 + t/3, j = t%3)
            {
                int gy = ty * 128 + (r - 1) - 32;
                uint64_t w = 0;
                if ((unsigned)gy < (unsigned)IMG_H) {
                    const uint64_t* gimg = gin + (size_t)tb * IMG_WORDS;
                    uint64_t gl = *wadr(gimg, gy, 2 * tx - 1 + jl);
                    uint64_t gr = *wadr(gimg, gy, 2 * tx + jl);
                    w = (gl >> 32) | (gr << 32);
                }
                lbuf[0][ci] = w;
            }
            __syncthreads();

            int cur = 0;
            uint64_t myrem = 0;
            int quiet = 0;
            #pragma unroll 1
            for (int ss = 0; ss < 2 * R_ITERS; ++ss) {
                const uint64_t* src = lbuf[cur];
                uint64_t* dst = lbuf[cur ^ 1];
                const uint64_t* cp = src + ci;
                uint64_t cond;
                uint64_t nw = thin_core(cp[-6], cp[-5], cp[-4],
                                        cp[-1], cp[0],  cp[1],
                                        cp[4],  cp[5],  cp[6], ss & 1, &cond);
                dst[ci] = nw;
                if (own_r) myrem |= cond & omask;
                int changed = __syncthreads_or(cond != 0 ? 1 : 0);  // also the barrier
                cur ^= 1;
                if (changed) quiet = 0;
                else if (++quiet >= 2) break;  // fixed point of both parities
            }

            // write back own 128x128 (region rows 33..160, cols 32..159)
            uint64_t* go = gout + (size_t)tb * IMG_WORDS;
            for (int t = threadIdx.x; t < 256; t += TTPB) {
                int rr = 33 + (t >> 1), kk = t & 1;
                uint64_t wa = lbuf[cur][rr * TLW2 + 1 + kk];
                uint64_t wb = lbuf[cur][rr * TLW2 + 2 + kk];
                *wadr(go, ty * 128 + (rr - 33), 2 * tx + kk) = (wa >> 32) | (wb << 32);
            }
            if (threadIdx.x == 0) sflag = 0;
            __syncthreads();
            if (__any(myrem != 0) && (threadIdx.x & 63) == 0) sflag = 1;
            __syncthreads();
            if (threadIdx.x == 0) {
                chgCur[tile] = (uint8_t)sflag;
                if (sflag) atomicOr(anyChg + m, 1);   // device-scope
            }
        } else {
            if (threadIdx.x == 0) chgCur[tile] = 0;   // slot already correct
        }

        if (m + 1 < MACROS) {
            __threadfence();
            grid.sync();
            // global convergence: nothing changed anywhere this macro ->
            // skeleton complete and identical in BOTH buffers -> bitA valid.
            if (threadIdx.x == 0)
                sflag = __hip_atomic_load(anyChg + m, __ATOMIC_RELAXED,
                                          __HIP_MEMORY_SCOPE_AGENT);
            __syncthreads();
            if (sflag == 0) break;
        }
    }
}

// ---- kernel C: fused direction trigger + weighted CE + reduce ----
__global__ __launch_bounds__(TPB) void loss_kernel(const float* __restrict__ logits,
                                                   const int* __restrict__ target,
                                                   const uint64_t* __restrict__ skel,
                                                   float* __restrict__ out) {
    __shared__ float wsum[TPB / 64];
    const int gtid = blockIdx.x * TPB + threadIdx.x;
    const int lane = threadIdx.x & 63;
    const int gwave = gtid >> 6;               // 0..4095
    const int dir = lane & 3;
    const int wi = gwave * 16 + (lane >> 2);   // interior word id, 0..65535
    const int b = wi >> 14, r2 = wi & 16383, y = r2 >> 4, k = r2 & 15;
    const uint64_t* r = wadr(skel + (size_t)b * IMG_WORDS, y, k);
    uint64_t tg;
    if (dir == 0)      tg = dir_trig<0, 1>(r, y, k);
    else if (dir == 1) tg = dir_trig<1, 0>(r, y, k);
    else if (dir == 2) tg = dir_trig<1, 1>(r, y, k);
    else               tg = dir_trig<1, -1>(r, y, k);
    tg |= __shfl_xor(tg, 1);
    tg |= __shfl_xor(tg, 2);                   // all 4 lanes: full trigger word

    const int base_rem = (y << 10) + (k << 6);
    const float* p0 = logits + (size_t)(2 * b) * HW + base_rem;
    const float* p1 = p0 + HW;
    const int* pt = target + (size_t)b * HW + base_rem;
    float acc = 0.0f;
    #pragma unroll
    for (int t = 0; t < 4; ++t) {
        const int px = t * 16 + dir * 4;       // 4-lane group covers 16 consec px
        float4 a = *reinterpret_cast<const float4*>(p0 + px);
        float4 bv = *reinterpret_cast<const float4*>(p1 + px);
        int4 tv = *reinterpret_cast<const int4*>(pt + px);
        unsigned bits4 = (unsigned)(tg >> px) & 0xFu;
        float l0[4] = {a.x, a.y, a.z, a.w};
        float l1[4] = {bv.x, bv.y, bv.z, bv.w};
        int tgt[4] = {tv.x, tv.y, tv.z, tv.w};
        #pragma unroll
        for (int e = 0; e < 4; ++e) {
            float s = tgt[e] ? (l1[e] - l0[e]) : (l0[e] - l1[e]);
            float ce = __logf(1.0f + __expf(-s));
            float wgt = ((bits4 >> e) & 1) ? 10.0f : 4.0f;
            acc += wgt * ce;
        }
    }
    acc *= (1.0f / (float)NPIX);
    #pragma unroll
    for (int off = 32; off > 0; off >>= 1) acc += __shfl_down(acc, off);
    if (lane == 0) wsum[threadIdx.x >> 6] = acc;
    __syncthreads();
    if (threadIdx.x == 0) atomicAdd(out, wsum[0] + wsum[1] + wsum[2] + wsum[3]);
}

extern "C" void kernel_launch(void* const* d_in, const int* in_sizes, int n_in,
                              void* d_out, int out_size, void* d_ws, size_t ws_size,
                              hipStream_t stream) {
    const float* logits = (const float*)d_in[0];
    const int* target = (const int*)d_in[1];
    float* out = (float*)d_out;
    char* ws = (char*)d_ws;
    int* anyChg = (int*)ws;                        // 8 ints at ws[0..32)
    uint64_t* bitA = (uint64_t*)(ws + 1024);
    uint64_t* bitB = bitA + (size_t)IMG_B * IMG_WORDS;
    uint8_t* chgA = (uint8_t*)(bitB + (size_t)IMG_B * IMG_WORDS);
    uint8_t* chgB = chgA + NTILES;

    hipMemsetAsync(d_out, 0, sizeof(float), stream);
    hipMemsetAsync(anyChg, 0, MACROS * sizeof(int), stream);
    mask_kernel<<<2048, TPB, 0, stream>>>(logits, bitA, bitB);
    {
        void* args[] = {(void*)&bitA, (void*)&bitB, (void*)&chgA, (void*)&chgB,
                        (void*)&anyChg};
        hipLaunchCooperativeKernel((const void*)thin_coop, dim3(NTILES),
                                   dim3(TTPB), args, 0, stream);
    }
    // converged-or-8-macros: skeleton is in bitA (skip-invariant keeps it exact)
    loss_kernel<<<1024, TPB, 0, stream>>>(logits, target, bitA, out);
}

// Round 3
// 68.373 us; speedup vs baseline: 3.4466x; 3.4466x over previous
//
#include <hip/hip_runtime.h>
#include <stdint.h>

// DirectionLoss: mask -> Zhang-Suen (bit-sliced, LDS-tiled 128x128-own tiles,
// per-iteration block-local early exit, per-tile activity skip, trapezoid
// halo trim) -> fused direction-trigger + weighted CE reduce.
// Structure: 10 plain dispatches (mask, 8 thin macros, loss). No grid.sync
// (measured ~20us/sync), no per-substep ballot skip (measured +10us overhead).
//
// Global bit layout per image: padded rows [1032][18] u64 (4 pad rows each side,
// 1 pad word each side), interior word (y,k): y in [0,1024), k in [0,16).
// ws: [0,1024) unused; bitA, bitB (each 4*18576 u64); chgA, chgB (256 B each).

#define IMG_B 4
#define IMG_H 1024
#define IMG_W 1024
#define HW (IMG_H * IMG_W)
#define NPIX (IMG_B * HW)
#define TPB 256
#define KW 18
#define ROWS 1032
#define IMG_WORDS (KW * ROWS)          // 18576
#define NW_INT (IMG_B * IMG_H * 16)    // 65536 interior words

// thinning: own 128x128 per tile, halo 32 -> region 192x192, <=16 iters/macro
#define R_ITERS 16
#define MACROS 8                       // 8*16 = 128 = MAX_THIN_ITERS
#define NTILES 256                     // 8x8x4, one block per tile
#define TTPB 576                       // 192 rows x 3 words, 1 word/thread
#define TLW2 5                         // LDS u64 per row: [pad, w0, w1, w2, pad]
#define TROWS2 194
#define TW2 (TROWS2 * TLW2)            // 970

__device__ __forceinline__ uint64_t* wadr(uint64_t* img, int y, int k) {
    return img + (size_t)(y + 4) * KW + (k + 1);
}
__device__ __forceinline__ const uint64_t* wadr(const uint64_t* img, int y, int k) {
    return img + (size_t)(y + 4) * KW + (k + 1);
}

__device__ __forceinline__ uint64_t eq2_5(uint64_t a, uint64_t b, uint64_t c,
                                          uint64_t d, uint64_t e) {
    uint64_t ab = a ^ b;
    uint64_t s1 = ab ^ c;
    uint64_t c1 = (a & b) | (c & ab);
    uint64_t t1 = s1 & d;
    uint64_t s2 = s1 ^ d;
    uint64_t t2 = s2 & e;
    uint64_t s3 = s2 ^ e;
    uint64_t ct = c1 ^ t1;
    uint64_t w2s = ct ^ t2;
    uint64_t w2c = (c1 & t1) | (t2 & ct);
    return ~s3 & w2s & ~w2c;
}

__device__ __forceinline__ uint64_t thin_core(uint64_t nL, uint64_t nC, uint64_t nR,
                                              uint64_t cL, uint64_t cC, uint64_t cR,
                                              uint64_t sL, uint64_t sC, uint64_t sR,
                                              int sub, uint64_t* cond_out) {
    uint64_t P2 = nC, P6 = sC;
    uint64_t P9 = (nC << 1) | (nL >> 63), P3 = (nC >> 1) | (nR << 63);
    uint64_t P8 = (cC << 1) | (cL >> 63), P4 = (cC >> 1) | (cR << 63);
    uint64_t P7 = (sC << 1) | (sL >> 63), P5 = (sC >> 1) | (sR << 63);

    // Bc in [2,6] via bitsliced 8-way popcount
    uint64_t sa = P2 ^ P3, ca = P2 & P3;
    uint64_t sb = P4 ^ P5, cb = P4 & P5;
    uint64_t sc2 = P6 ^ P7, cc2 = P6 & P7;
    uint64_t sd = P8 ^ P9, cd = P8 & P9;
    uint64_t t0x = sa & sb, u0 = sa ^ sb;
    uint64_t v0x = ca ^ cb, v0 = v0x ^ t0x;
    uint64_t w0 = (ca & cb) | (t0x & v0x);
    uint64_t t1x = sc2 & sd, u1 = sc2 ^ sd;
    uint64_t v1x = cc2 ^ cd, v1 = v1x ^ t1x;
    uint64_t w1 = (cc2 & cd) | (t1x & v1x);
    uint64_t b0 = u0 ^ u1, g0 = u0 & u1;
    uint64_t b1x = v0 ^ v1, b1 = b1x ^ g0;
    uint64_t g1 = (v0 & v1) | (g0 & b1x);
    uint64_t b2x = w0 ^ w1, b2 = b2x ^ g1;
    uint64_t b3 = (w0 & w1) | (g1 & b2x);
    uint64_t ge2 = b1 | b2 | b3;
    uint64_t le6 = ~(b3 | (b2 & b1 & b0));

    // A == 1: exactly one 0->1 transition around the ring (shallow tree)
    uint64_t t0 = ~P2 & P3, t1 = ~P3 & P4, t2 = ~P4 & P5, t3 = ~P5 & P6;
    uint64_t t4 = ~P6 & P7, t5 = ~P7 & P8, t6 = ~P8 & P9, t7 = ~P9 & P2;
    uint64_t s0 = t0 | t1, d0 = t0 & t1;
    uint64_t s1 = t2 | t3, d1 = t2 & t3;
    uint64_t s2 = t4 | t5, d2 = t4 & t5;
    uint64_t s3 = t6 | t7, d3 = t6 & t7;
    uint64_t sA = s0 | s1, dA = d0 | d1 | (s0 & s1);
    uint64_t sB = s2 | s3, dB = d2 | d3 | (s2 & s3);
    uint64_t any1 = sA | sB;
    uint64_t any2 = dA | dB | (sA & sB);
    uint64_t A1 = any1 & ~any2;

    uint64_t cond = cC & ge2 & le6 & A1;
    if (sub == 0) cond &= ~(P2 & P4 & P6) & ~(P4 & P6 & P8);
    else          cond &= ~(P2 & P4 & P8) & ~(P2 & P6 & P8);
    *cond_out = cond;
    return cC & ~cond;
}

template<int DY, int DX>
__device__ __forceinline__ uint64_t dir_trig(const uint64_t* r, int y, int k) {
    uint64_t sh[9];
    uint64_t any = 0;
    #pragma unroll
    for (int j = -4; j <= 4; ++j) {
        const uint64_t* rr = r + j * DY * KW;
        const int s = j * DX;
        uint64_t w = rr[0], v;
        if (s > 0)      v = (w >> s) | (rr[1] << (64 - s));
        else if (s < 0) v = (w << (-s)) | (rr[-1] >> (64 + s));
        else            v = w;
        sh[j + 4] = v; any |= v;
    }
    if (!any) return 0;
    uint64_t trig = 0;
    #pragma unroll
    for (int o = -2; o <= 2; ++o) {
        uint64_t E = eq2_5(sh[o + 2], sh[o + 3], sh[o + 4], sh[o + 5], sh[o + 6]);
        if (DY != 0) {
            int qy = y + o * DY;
            if ((unsigned)qy >= (unsigned)IMG_H) E = 0;
        }
        const int s = o * DX;
        if (s < 0)      { if (k == 0)  E &= (~0ull) << (-s); }
        else if (s > 0) { if (k == 15) E &= (~0ull) >> s; }
        trig |= E;
    }
    return trig;
}

// ---- kernel A: zero out + pads of both bit buffers, build mask bitmap ----
__global__ __launch_bounds__(TPB) void mask_kernel(const float* __restrict__ logits,
                                                   uint64_t* __restrict__ bitA,
                                                   uint64_t* __restrict__ bitB,
                                                   float* __restrict__ out) {
    const int gtid = blockIdx.x * TPB + threadIdx.x;
    const int gsz = gridDim.x * TPB;
    const int wid = gtid >> 6, lane = gtid & 63, nwv = gsz >> 6;

    if (gtid == 0) *out = 0.0f;        // replaces the d_out memset dispatch
    for (int i = gtid; i < IMG_B * IMG_WORDS; i += gsz) {
        int w = i % IMG_WORDS;
        int row = w / KW, col = w - row * KW;
        if (row < 4 || row >= ROWS - 4 || col == 0 || col == KW - 1) {
            bitA[i] = 0; bitB[i] = 0;
        }
    }
    for (int w = wid; w < NW_INT; w += nwv) {
        int b = w >> 14, r2 = w & 16383, y = r2 >> 4, k = r2 & 15;
        int rem = (y << 10) + (k << 6) + lane;
        const float* p0 = logits + (size_t)(2 * b) * HW + rem;
        float l0 = p0[0], l1 = p0[HW];
        uint64_t mask = __ballot(l1 >= l0);
        if (lane == 0) *wadr(bitA + (size_t)b * IMG_WORDS, y, k) = mask;
    }
}

// ---- kernel B: one <=16-iteration thinning macro ----
// pair-structured substeps (1 or-reduce per iteration), trapezoid halo trim,
// center word held in a register.
__global__ __launch_bounds__(TTPB) void thin_kernel(const uint64_t* __restrict__ gin,
                                                    uint64_t* __restrict__ gout,
                                                    const uint8_t* __restrict__ chgPrev,
                                                    uint8_t* __restrict__ chgCur, int m) {
    __shared__ uint64_t lbuf[2][TW2];
    __shared__ int sflag;
    const int tile = blockIdx.x;
    const int tx = tile & 7, ty = (tile >> 3) & 7, tb = tile >> 6;

    if (m > 0) {
        if (threadIdx.x == 0) sflag = 0;
        __syncthreads();
        if (threadIdx.x < 9) {
            int dxn = (int)threadIdx.x % 3 - 1, dyn = (int)threadIdx.x / 3 - 1;
            int nx = tx + dxn, ny = ty + dyn;
            if ((unsigned)nx < 8u && (unsigned)ny < 8u &&
                chgPrev[tb * 64 + ny * 8 + nx]) sflag = 1;  // benign race
        }
        __syncthreads();
        if (sflag == 0) {                     // neighborhood static last macro:
            if (threadIdx.x == 0) chgCur[tile] = 0;  // slot already correct
            return;
        }
    }

    // zero LDS pads (never overwritten afterwards)
    for (int i = threadIdx.x; i < TW2; i += TTPB) {
        int c = i % TLW2, rr = i / TLW2;
        if (c == 0 || c == TLW2 - 1 || rr == 0 || rr == TROWS2 - 1) {
            lbuf[0][i] = 0; lbuf[1][i] = 0;
        }
    }
    // load region 192 rows x 3 words: thread t -> (r = 1 + t/3, j = t%3)
    const int r = 1 + (int)threadIdx.x / 3, jl = (int)threadIdx.x % 3;
    const int ci = r * TLW2 + 1 + jl;
    uint64_t v = 0;   // own word, kept in a register across substeps
    {
        int gy = ty * 128 + (r - 1) - 32;
        if ((unsigned)gy < (unsigned)IMG_H) {
            const uint64_t* gimg = gin + (size_t)tb * IMG_WORDS;
            uint64_t gl = *wadr(gimg, gy, 2 * tx - 1 + jl);
            uint64_t gr = *wadr(gimg, gy, 2 * tx + jl);
            v = (gl >> 32) | (gr << 32);
        }
        lbuf[0][ci] = v;
    }
    __syncthreads();

    const uint64_t omask = (jl == 0) ? 0xFFFFFFFF00000000ull
                         : (jl == 1) ? ~0ull : 0x00000000FFFFFFFFull;
    const bool own_r = (r >= 33) && (r <= 160);
    // trapezoid: row-distance from the own tile; a word at distance d only
    // influences the own tile's final state at substep ss if d + ss < 2*R.
    const int d = (r < 33) ? (33 - r) : ((r > 160) ? (r - 160) : 0);
    uint64_t myrem = 0;
    #pragma unroll 1
    for (int it = 0; it < R_ITERS; ++it) {
        uint64_t cond0 = 0, cond1 = 0;
        {   // substep A: lbuf[0] -> lbuf[1]
            if (d + 2 * it < 2 * R_ITERS) {
                const uint64_t* cp = lbuf[0] + ci;
                v = thin_core(cp[-6], cp[-5], cp[-4],
                              cp[-1], v,      cp[1],
                              cp[4],  cp[5],  cp[6], 0, &cond0);
            }
            lbuf[1][ci] = v;
        }
        __syncthreads();
        {   // substep B: lbuf[1] -> lbuf[0]
            if (d + 2 * it + 1 < 2 * R_ITERS) {
                const uint64_t* cp = lbuf[1] + ci;
                v = thin_core(cp[-6], cp[-5], cp[-4],
                              cp[-1], v,      cp[1],
                              cp[4],  cp[5],  cp[6], 1, &cond1);
            }
            lbuf[0][ci] = v;
        }
        if (own_r) myrem |= (cond0 | cond1) & omask;
        // one or-reduce per ZS iteration (also the barrier); a full iteration
        // with no deletions anywhere -> fixpoint of both parities -> identity.
        int changed = __syncthreads_or((cond0 | cond1) != 0 ? 1 : 0);
        if (!changed) break;
    }

    // write back own 128x128 (region rows 33..160, cols 32..159) from lbuf[0]
    uint64_t* go = gout + (size_t)tb * IMG_WORDS;
    for (int t = threadIdx.x; t < 256; t += TTPB) {
        int rr = 33 + (t >> 1), kk = t & 1;
        uint64_t wa = lbuf[0][rr * TLW2 + 1 + kk];
        uint64_t wb = lbuf[0][rr * TLW2 + 2 + kk];
        *wadr(go, ty * 128 + (rr - 33), 2 * tx + kk) = (wa >> 32) | (wb << 32);
    }
    if (threadIdx.x == 0) sflag = 0;
    __syncthreads();
    if (__any(myrem != 0) && (threadIdx.x & 63) == 0) sflag = 1;
    __syncthreads();
    if (threadIdx.x == 0) chgCur[tile] = (uint8_t)sflag;
}

// ---- kernel C: fused direction trigger + weighted CE + reduce ----
__global__ __launch_bounds__(TPB) void loss_kernel(const float* __restrict__ logits,
                                                   const int* __restrict__ target,
                                                   const uint64_t* __restrict__ skel,
                                                   float* __restrict__ out) {
    __shared__ float wsum[TPB / 64];
    const int gtid = blockIdx.x * TPB + threadIdx.x;
    const int lane = threadIdx.x & 63;
    const int gwave = gtid >> 6;               // 0..4095
    const int dir = lane & 3;
    const int wi = gwave * 16 + (lane >> 2);   // interior word id, 0..65535
    const int b = wi >> 14, r2 = wi & 16383, y = r2 >> 4, k = r2 & 15;
    const uint64_t* r = wadr(skel + (size_t)b * IMG_WORDS, y, k);
    uint64_t tg;
    if (dir == 0)      tg = dir_trig<0, 1>(r, y, k);
    else if (dir == 1) tg = dir_trig<1, 0>(r, y, k);
    else if (dir == 2) tg = dir_trig<1, 1>(r, y, k);
    else               tg = dir_trig<1, -1>(r, y, k);
    tg |= __shfl_xor(tg, 1);
    tg |= __shfl_xor(tg, 2);                   // all 4 lanes: full trigger word

    const int base_rem = (y << 10) + (k << 6);
    const float* p0 = logits + (size_t)(2 * b) * HW + base_rem;
    const float* p1 = p0 + HW;
    const int* pt = target + (size_t)b * HW + base_rem;
    float acc = 0.0f;
    #pragma unroll
    for (int t = 0; t < 4; ++t) {
        const int px = t * 16 + dir * 4;       // 4-lane group covers 16 consec px
        float4 a = *reinterpret_cast<const float4*>(p0 + px);
        float4 bv = *reinterpret_cast<const float4*>(p1 + px);
        int4 tv = *reinterpret_cast<const int4*>(pt + px);
        unsigned bits4 = (unsigned)(tg >> px) & 0xFu;
        float l0[4] = {a.x, a.y, a.z, a.w};
        float l1[4] = {bv.x, bv.y, bv.z, bv.w};
        int tgt[4] = {tv.x, tv.y, tv.z, tv.w};
        #pragma unroll
        for (int e = 0; e < 4; ++e) {
            float s = tgt[e] ? (l1[e] - l0[e]) : (l0[e] - l1[e]);
            float ce = __logf(1.0f + __expf(-s));
            float wgt = ((bits4 >> e) & 1) ? 10.0f : 4.0f;
            acc += wgt * ce;
        }
    }
    acc *= (1.0f / (float)NPIX);
    #pragma unroll
    for (int off = 32; off > 0; off >>= 1) acc += __shfl_down(acc, off);
    if (lane == 0) wsum[threadIdx.x >> 6] = acc;
    __syncthreads();
    if (threadIdx.x == 0) atomicAdd(out, wsum[0] + wsum[1] + wsum[2] + wsum[3]);
}

extern "C" void kernel_launch(void* const* d_in, const int* in_sizes, int n_in,
                              void* d_out, int out_size, void* d_ws, size_t ws_size,
                              hipStream_t stream) {
    const float* logits = (const float*)d_in[0];
    const int* target = (const int*)d_in[1];
    float* out = (float*)d_out;
    char* ws = (char*)d_ws;
    uint64_t* bitA = (uint64_t*)(ws + 1024);
    uint64_t* bitB = bitA + (size_t)IMG_B * IMG_WORDS;
    uint8_t* chgA = (uint8_t*)(bitB + (size_t)IMG_B * IMG_WORDS);
    uint8_t* chgB = chgA + NTILES;

    mask_kernel<<<2048, TPB, 0, stream>>>(logits, bitA, bitB, out);
    for (int m = 0; m < MACROS; ++m) {
        const uint64_t* in = (m & 1) ? bitB : bitA;
        uint64_t* ob = (m & 1) ? bitA : bitB;
        const uint8_t* cp = (m & 1) ? chgA : chgB;   // written at macro m-1
        uint8_t* cc = (m & 1) ? chgB : chgA;         // written at macro m
        thin_kernel<<<NTILES, TTPB, 0, stream>>>(in, ob, cp, cc, m);
    }
    // after 8 macros (even), skeleton is in bitA (skip-invariant keeps it exact)
    loss_kernel<<<1024, TPB, 0, stream>>>(logits, target, bitA, out);
}